// Round 10
// baseline (193.909 us; speedup 1.0000x reference)
//
#include <hip/hip_runtime.h>
#include <hip/hip_cooperative_groups.h>
#include <math.h>

namespace cg = cooperative_groups;

// B=32, C=3, H=W=512. Low-pass keeps freqs {0,1,2,-3,-2,-1} in both dims.
// Primary: ONE cooperative kernel (grid sized by occupancy query), 3 phases:
//   A: column transform (radix-2 fold over h), grid-stride over 3072 units
//      -> Apart[img][8][plane 8][512]
//   B: blocks 0..95 reduce partials + project -> F[img][56]; block 96 builds
//      synthesis table tabS[512][12]
//   C: grid-stride over 4096 output tiles: per-row T[c][kc], per-pixel synth,
//      |.|, MLP 3->8 relu ->3, +lp, clip
// Fallback (if coop launch rejected): round-8's 3-kernel pipeline.
//
// ws (floats): tabS @0 (6144), F @6144 (5376), Apart @12288 (3.15M) ~12.6 MB.

#define WS_TS 0
#define WS_F  6144
#define WS_A  12288
constexpr int NPART = 8;

// cos/sin(2*pi*n/512), n = 0..7
#define CJ0 1.0f
#define CJ1 0.99992470183914450299f
#define CJ2 0.99969881869620422012f
#define CJ3 0.99932238458834954375f
#define CJ4 0.99879545620517239271f
#define CJ5 0.99811811290014917919f
#define CJ6 0.99729045667869021614f
#define CJ7 0.99631261218277800129f
#define SJ0 0.0f
#define SJ1 0.01227153828571992539f
#define SJ2 0.02454122852291228803f
#define SJ3 0.03680722294135883171f
#define SJ4 0.04906767432741801425f
#define SJ5 0.06132073630220857829f
#define SJ6 0.07356456359966742631f
#define SJ7 0.08579731234443989385f

// ---------------- shared phase bodies (device inline) ----------------

__device__ __forceinline__ void phaseA_unit(const float* __restrict__ x,
                                            float* __restrict__ A,
                                            float* __restrict__ smem,
                                            int unit, int t) {
    float (*buf)[64][15] = (float (*)[64][15])smem;
    const float TH = 6.28318530717958647692f / 512.0f;
    int wave = t >> 6, lane = t & 63;
    int img = unit >> 5;
    int sub = unit & 31;
    int stripe = sub & 3;
    int hgrp = sub >> 2;
    int w = stripe * 128 + lane * 2;
    int H = hgrp * 32 + wave * 8;
    const float* xp = x + (size_t)img * 262144 + (size_t)H * 512 + w;

    float pc1, ps1, pc2, ps2, pc3, ps3;
    sincosf(TH * (float)H, &ps1, &pc1);
    pc2 = pc1 * pc1 - ps1 * ps1;  ps2 = 2.f * pc1 * ps1;
    pc3 = pc1 * pc2 - ps1 * ps2;  ps3 = ps1 * pc2 + pc1 * ps2;

    float s0[2] = {0, 0};
    float ar1[2] = {0, 0}, ai1[2] = {0, 0};
    float ar2[2] = {0, 0}, ai2[2] = {0, 0};
    float ar3[2] = {0, 0}, ai3[2] = {0, 0};

#define ROW(J, CJ, SJ)                                                        \
    {                                                                         \
        float2 xa = *(const float2*)(xp + (size_t)(J) * 512);                 \
        float2 xb = *(const float2*)(xp + (size_t)((J) * 512 + 131072));      \
        float u0 = xa.x + xb.x, u1 = xa.y + xb.y;                             \
        float v0 = xa.x - xb.x, v1 = xa.y - xb.y;                             \
        float cj1 = pc1 * (CJ) - ps1 * (SJ);                                  \
        float sj1 = ps1 * (CJ) + pc1 * (SJ);                                  \
        float cj2 = cj1 * cj1 - sj1 * sj1;                                    \
        float sj2 = 2.f * cj1 * sj1;                                          \
        float cj3 = cj1 * cj2 - sj1 * sj2;                                    \
        float sj3 = sj1 * cj2 + cj1 * sj2;                                    \
        s0[0] += u0;               s0[1] += u1;                               \
        ar1[0] = fmaf(v0, cj1, ar1[0]);  ai1[0] = fmaf(-v0, sj1, ai1[0]);     \
        ar1[1] = fmaf(v1, cj1, ar1[1]);  ai1[1] = fmaf(-v1, sj1, ai1[1]);     \
        ar2[0] = fmaf(u0, cj2, ar2[0]);  ai2[0] = fmaf(-u0, sj2, ai2[0]);     \
        ar2[1] = fmaf(u1, cj2, ar2[1]);  ai2[1] = fmaf(-u1, sj2, ai2[1]);     \
        ar3[0] = fmaf(v0, cj3, ar3[0]);  ai3[0] = fmaf(-v0, sj3, ai3[0]);     \
        ar3[1] = fmaf(v1, cj3, ar3[1]);  ai3[1] = fmaf(-v1, sj3, ai3[1]);     \
    }
    ROW(0, CJ0, SJ0)
    ROW(1, CJ1, SJ1)
    ROW(2, CJ2, SJ2)
    ROW(3, CJ3, SJ3)
    ROW(4, CJ4, SJ4)
    ROW(5, CJ5, SJ5)
    ROW(6, CJ6, SJ6)
    ROW(7, CJ7, SJ7)
#undef ROW

    if (wave != 0) {
        float* r = &buf[wave - 1][lane][0];
        r[0] = s0[0];   r[1] = s0[1];
        r[2] = ar1[0];  r[3] = ar1[1];  r[4] = ai1[0];  r[5] = ai1[1];
        r[6] = ar2[0];  r[7] = ar2[1];  r[8] = ai2[0];  r[9] = ai2[1];
        r[10] = ar3[0]; r[11] = ar3[1]; r[12] = ai3[0]; r[13] = ai3[1];
    }
    __syncthreads();
    if (wave == 0) {
#pragma unroll
        for (int v = 0; v < 3; ++v) {
            const float* r = &buf[v][lane][0];
            s0[0] += r[0];   s0[1] += r[1];
            ar1[0] += r[2];  ar1[1] += r[3];  ai1[0] += r[4];  ai1[1] += r[5];
            ar2[0] += r[6];  ar2[1] += r[7];  ai2[0] += r[8];  ai2[1] += r[9];
            ar3[0] += r[10]; ar3[1] += r[11]; ai3[0] += r[12]; ai3[1] += r[13];
        }
        float* Ab = A + (((size_t)img * NPART + hgrp) * 8) * 512 + w;
        *(float2*)(Ab + 0 * 512) = make_float2(s0[0], s0[1]);
        *(float2*)(Ab + 1 * 512) = make_float2(0.f, 0.f);
        *(float2*)(Ab + 2 * 512) = make_float2(ar1[0], ar1[1]);
        *(float2*)(Ab + 3 * 512) = make_float2(ai1[0], ai1[1]);
        *(float2*)(Ab + 4 * 512) = make_float2(ar2[0], ar2[1]);
        *(float2*)(Ab + 5 * 512) = make_float2(ai2[0], ai2[1]);
        *(float2*)(Ab + 6 * 512) = make_float2(ar3[0], ar3[1]);
        *(float2*)(Ab + 7 * 512) = make_float2(ai3[0], ai3[1]);
    }
    __syncthreads();
}

__device__ __forceinline__ void phaseB_table(float* __restrict__ ws, int t) {
    const float TH = 6.28318530717958647692f / 512.0f;
    const int mv[6] = {0, 1, 2, -3, -2, -1};
    for (int h = t; h < 512; h += 256) {
        float* tsp = ws + WS_TS + h * 12;
#pragma unroll
        for (int i = 0; i < 6; ++i) {
            int r = ((mv[i] * h) % 512 + 512) & 511;
            float s, c;
            sincosf(TH * (float)r, &s, &c);
            tsp[2 * i] = c; tsp[2 * i + 1] = s;
        }
    }
}

__device__ __forceinline__ void phaseB_proj(const float* __restrict__ A,
                                            float* __restrict__ F,
                                            float* __restrict__ smem,
                                            int img, int t) {
    float (*As)[8][68] = (float (*)[8][68])smem;          // 4352 floats
    float (*Rs)[8][2] = (float (*)[8][2])(smem + 4352);   // 448 floats
    const float TH = 6.28318530717958647692f / 512.0f;
    {
        int plane = t >> 5;
        int w0 = (t & 31) * 16;
        float4 acc[4];
#pragma unroll
        for (int u = 0; u < 4; ++u) acc[u] = make_float4(0.f, 0.f, 0.f, 0.f);
        const float* base = A + ((size_t)img * NPART * 8 + plane) * 512 + w0;
        for (int hg = 0; hg < NPART; ++hg) {
            const float* p = base + (size_t)hg * 8 * 512;
#pragma unroll
            for (int u = 0; u < 4; ++u) {
                float4 v = *(const float4*)(p + u * 4);
                acc[u].x += v.x; acc[u].y += v.y; acc[u].z += v.z; acc[u].w += v.w;
            }
        }
        int seg = w0 >> 6, j0 = w0 & 63;
#pragma unroll
        for (int u = 0; u < 4; ++u)
            *(float4*)&As[plane][seg][j0 + u * 4] = acc[u];
    }
    __syncthreads();
    if (t < 224) {
        int pair = t >> 3, seg = t & 7;
        int k = pair / 7, mi = pair % 7;
        float m = (float)(mi - 3);
        float cm, sm, pc, ps;
        sincosf(-m * TH, &sm, &cm);
        sincosf(-m * TH * (float)(seg * 64), &ps, &pc);
        const float* Ar_ = &As[2 * k][seg][0];
        const float* Ai_ = &As[2 * k + 1][seg][0];
        float pre = 0.f, pim = 0.f;
#pragma unroll 4
        for (int j = 0; j < 64; ++j) {
            float Ar = Ar_[j], Ai = Ai_[j];
            pre += Ar * pc - Ai * ps;
            pim += Ar * ps + Ai * pc;
            float n = pc * cm - ps * sm;
            ps = ps * cm + pc * sm;
            pc = n;
        }
        Rs[pair][seg][0] = pre;
        Rs[pair][seg][1] = pim;
    }
    __syncthreads();
    if (t < 56) {
        int pair = t >> 1, part = t & 1;
        float s = 0.f;
#pragma unroll
        for (int g = 0; g < 8; ++g) s += Rs[pair][g][part];
        F[(size_t)img * 56 + t] = s;
    }
    __syncthreads();
}

__device__ __forceinline__ void phaseC_tile(const float* __restrict__ ws,
                                            const float rw1[8][3], const float rb1[8],
                                            const float rw2[3][8], const float rb2[3],
                                            float* __restrict__ out,
                                            float* __restrict__ smem,
                                            int tile, int t) {
    const float* tabS = ws + WS_TS;
    const float* Fb = ws + WS_F;
    float (*F_lds)[56] = (float (*)[56])smem;
    float (*T)[3][12] = (float (*)[3][12])(smem + 168);
    int b = tile >> 7;
    int h0 = (tile & 127) << 2;
    __syncthreads();
    if (t < 168) {
        int c = t / 56, comp = t % 56;
        F_lds[c][comp] = Fb[(size_t)(b * 3 + c) * 56 + comp];
    }
    __syncthreads();
    if (t < 72) {
        int rl = t / 18, rem = t % 18;
        int c = rem / 6, kc = rem % 6;
        int h = h0 + rl;
        const float* th = tabS + h * 12;
        int m_kc = (kc < 3) ? kc : kc - 6;
        const float inv = 1.0f / (512.0f * 512.0f);
        float tre = 0.f, tim = 0.f;
#pragma unroll
        for (int kr = 0; kr < 6; ++kr) {
            int kk, mi; float csign;
            if (kr < 3) { kk = kr;     mi = m_kc + 3; csign =  1.f; }
            else        { kk = 6 - kr; mi = 3 - m_kc; csign = -1.f; }
            int pair = kk * 7 + mi;
            float fr = F_lds[c][pair * 2] * inv;
            float fi = F_lds[c][pair * 2 + 1] * csign * inv;
            float cc = th[kr * 2], ss = th[kr * 2 + 1];
            tre += fr * cc - fi * ss;
            tim += fr * ss + fi * cc;
        }
        T[rl][c][kc * 2]     = tre;
        T[rl][c][kc * 2 + 1] = tim;
    }
    __syncthreads();

    int rl = t >> 6, lane = t & 63;
    int h = h0 + rl;
    float A0r[3], A0i[3], U1r[3], U1i[3], V1r[3], V1i[3];
    float U2r[3], U2i[3], V2r[3], V2i[3], Br[3], Bi[3];
#pragma unroll
    for (int c = 0; c < 3; ++c) {
        const float* Tc = T[rl][c];
        A0r[c] = Tc[0];  A0i[c] = Tc[1];
        float t1r = Tc[2],  t1i = Tc[3];
        float t2r = Tc[4],  t2i = Tc[5];
        float bmr = Tc[6],  bmi = Tc[7];
        float m2r = Tc[8],  m2i = Tc[9];
        float m1r = Tc[10], m1i = Tc[11];
        U1r[c] = t1r + m1r; U1i[c] = t1i + m1i;
        V1r[c] = t1r - m1r; V1i[c] = t1i - m1i;
        U2r[c] = t2r + m2r; U2i[c] = t2i + m2i;
        V2r[c] = t2r - m2r; V2i[c] = t2i - m2i;
        Br[c] = bmr; Bi[c] = bmi;
    }
    const float* tw = tabS + lane * 12;
    float c1 = tw[2], s1 = tw[3];
    float c2 = tw[4], s2 = tw[5];
    float c3 = tw[6], s3 = -tw[7];
    const float K = 0.70710678118654752440f;
    float* ob = out + ((size_t)(b * 3) * 512 + h) * 512;

#pragma unroll
    for (int j = 0; j < 8; ++j) {
        int w = lane + 64 * j;
        float lp[3];
#pragma unroll
        for (int c = 0; c < 3; ++c) {
            float re = A0r[c] + U1r[c] * c1 - V1i[c] * s1
                              + U2r[c] * c2 - V2i[c] * s2
                              + Br[c] * c3 + Bi[c] * s3;
            float im = A0i[c] + U1i[c] * c1 + V1r[c] * s1
                              + U2i[c] * c2 + V2r[c] * s2
                              + Bi[c] * c3 - Br[c] * s3;
            lp[c] = sqrtf(re * re + im * im);
        }
        float hid[8];
#pragma unroll
        for (int f_ = 0; f_ < 8; ++f_) {
            float v = rb1[f_] + lp[0] * rw1[f_][0] + lp[1] * rw1[f_][1] + lp[2] * rw1[f_][2];
            hid[f_] = fmaxf(v, 0.0f);
        }
#pragma unroll
        for (int c = 0; c < 3; ++c) {
            float y = rb2[c] + lp[c];
#pragma unroll
            for (int f_ = 0; f_ < 8; ++f_) y += hid[f_] * rw2[c][f_];
            y = fminf(fmaxf(y, 0.0f), 1.0f);
            ob[(size_t)c * 262144 + w] = y;
        }
        if (j < 7) {
            float nc1 = K * (c1 - s1), ns1 = K * (c1 + s1);
            float nc2 = -s2,           ns2 = c2;
            float nc3 = -K * (c3 + s3), ns3 = K * (c3 - s3);
            c1 = nc1; s1 = ns1; c2 = nc2; s2 = ns2; c3 = nc3; s3 = ns3;
        }
    }
}

// ---------------- fused cooperative kernel ----------------

__global__ __launch_bounds__(256, 2) void k_fused(const float* __restrict__ x,
                                                  const float* __restrict__ w1,
                                                  const float* __restrict__ b1,
                                                  const float* __restrict__ w2,
                                                  const float* __restrict__ b2,
                                                  float* __restrict__ out,
                                                  float* __restrict__ ws) {
    cg::grid_group grid = cg::this_grid();
    __shared__ float smem[4800];
    int t = threadIdx.x;
    int bid = blockIdx.x;
    int nblk = gridDim.x;
    float* A = ws + WS_A;

    for (int unit = bid; unit < 3072; unit += nblk)
        phaseA_unit(x, A, smem, unit, t);
    grid.sync();

    if (bid == 96) phaseB_table(ws, t);
    else if (bid < 96) phaseB_proj(A, ws + WS_F, smem, bid, t);
    grid.sync();

    float rw1[8][3], rb1[8], rw2[3][8], rb2[3];
#pragma unroll
    for (int f_ = 0; f_ < 8; ++f_) {
        rb1[f_] = b1[f_];
#pragma unroll
        for (int c = 0; c < 3; ++c) rw1[f_][c] = w1[f_ * 3 + c];
    }
#pragma unroll
    for (int c = 0; c < 3; ++c) {
        rb2[c] = b2[c];
#pragma unroll
        for (int f_ = 0; f_ < 8; ++f_) rw2[c][f_] = w2[c * 8 + f_];
    }
    for (int tile = bid; tile < 4096; tile += nblk)
        phaseC_tile(ws, rw1, rb1, rw2, rb2, out, smem, tile, t);
}

// ---------------- fallback kernels (round-8 pipeline) ----------------

__global__ __launch_bounds__(256, 6) void k_colsum(const float* __restrict__ x,
                                                   float* __restrict__ ws) {
    __shared__ float smem[2880];
    phaseA_unit(x, ws + WS_A, smem, blockIdx.x, threadIdx.x);
}

__global__ __launch_bounds__(256) void k_proj(float* __restrict__ ws) {
    __shared__ float smem[4800];
    if (blockIdx.x == 96) { phaseB_table(ws, threadIdx.x); return; }
    phaseB_proj(ws + WS_A, ws + WS_F, smem, blockIdx.x, threadIdx.x);
}

__global__ __launch_bounds__(256) void k_out(const float* __restrict__ ws,
                                             const float* __restrict__ w1,
                                             const float* __restrict__ b1,
                                             const float* __restrict__ w2,
                                             const float* __restrict__ b2,
                                             float* __restrict__ out) {
    __shared__ float smem[320];
    int t = threadIdx.x;
    float rw1[8][3], rb1[8], rw2[3][8], rb2[3];
#pragma unroll
    for (int f_ = 0; f_ < 8; ++f_) {
        rb1[f_] = b1[f_];
#pragma unroll
        for (int c = 0; c < 3; ++c) rw1[f_][c] = w1[f_ * 3 + c];
    }
#pragma unroll
    for (int c = 0; c < 3; ++c) {
        rb2[c] = b2[c];
#pragma unroll
        for (int f_ = 0; f_ < 8; ++f_) rw2[c][f_] = w2[c * 8 + f_];
    }
    phaseC_tile(ws, rw1, rb1, rw2, rb2, out, smem, blockIdx.x, t);
}

extern "C" void kernel_launch(void* const* d_in, const int* in_sizes, int n_in,
                              void* d_out, int out_size, void* d_ws, size_t ws_size,
                              hipStream_t stream) {
    const float* x  = (const float*)d_in[0];
    const float* w1 = (const float*)d_in[1];
    const float* b1 = (const float*)d_in[2];
    const float* w2 = (const float*)d_in[3];
    const float* b2 = (const float*)d_in[4];
    float* out = (float*)d_out;
    float* ws = (float*)d_ws;

    bool coop_done = false;
    int maxActive = 0;
    if (hipOccupancyMaxActiveBlocksPerMultiprocessor(
            &maxActive, (const void*)k_fused, 256, 0) == hipSuccess &&
        maxActive >= 1) {
        int nblk = maxActive * 256;          // 256 CUs on MI355X
        if (nblk > 1024) nblk = 1024;
        void* args[] = {(void*)&x, (void*)&w1, (void*)&b1, (void*)&w2,
                        (void*)&b2, (void*)&out, (void*)&ws};
        hipError_t e = hipLaunchCooperativeKernel((const void*)k_fused,
                                                  dim3(nblk), dim3(256),
                                                  args, 0, stream);
        if (e == hipSuccess) coop_done = true;
        else (void)hipGetLastError();        // clear, fall through
    } else {
        (void)hipGetLastError();
    }

    if (!coop_done) {
        hipLaunchKernelGGL(k_colsum, dim3(96 * 32), dim3(256), 0, stream, x, ws);
        hipLaunchKernelGGL(k_proj, dim3(97), dim3(256), 0, stream, ws);
        hipLaunchKernelGGL(k_out, dim3(4096), dim3(256), 0, stream,
                           ws, w1, b1, w2, b2, out);
    }
}

// Round 11
// 64.535 us; speedup vs baseline: 3.0047x; 3.0047x over previous
//
#include <hip/hip_runtime.h>
#include <math.h>

// B=32, C=3, H=W=512. Low-pass keeps freqs {0,1,2,-3,-2,-1} in both dims.
// Pipeline (3 kernels):
//   k_colsum: per (img, 64-row hgrp): wave = 16-row window; 4 bursts of EIGHT
//             back-to-back contiguous dwordx4 loads (8KB/wave in flight), then
//             register FMA; twiddles from wave-uniform base phasor rotated by
//             compile-time constants. LDS-merge 4 waves ->
//             Apart[img][8][plane 8][512]
//   k_proj:   768 blocks = (img, 64-w segment): 8 upfront float2 loads reduce
//             partials -> As[8][64] LDS; 28 threads project (k,m) pairs by
//             phasor recurrence -> Ppart[img][seg][56]. Block 768 builds tabS.
//   k_out:    sum 8 seg-partials -> F; per-row T[c][kc]; per pixel synth via
//             register phasor recurrence, |.|, MLP 3->8 relu ->3, +lp, clip.
//
// ws (floats): tabS @0 (6144), Ppart @8192 (43008), Apart @65536 (3.15M) ~13 MB.

#define WS_TS 0
#define WS_PP 8192
#define WS_A  65536
constexpr int NPART = 8;

// cos/sin(2*pi*n/512)
#define CJ1 0.99992470183914450299f
#define CJ2 0.99969881869620422012f
#define CJ3 0.99932238458834954375f
#define CJ4 0.99879545620517239271f
#define SJ1 0.01227153828571992539f
#define SJ2 0.02454122852291228803f
#define SJ3 0.03680722294135883171f
#define SJ4 0.04906767432741801425f

// Block = (img, hgrp of 64 rows). 4 waves x 16 rows; lane owns w-quads at
// lane*4 (half A) and lane*4+256 (half B). Bursts are contiguous 8KB.
__global__ __launch_bounds__(256, 4) void k_colsum(const float* __restrict__ x,
                                                   float* __restrict__ ws) {
    __shared__ float buf[3][64][57];
    float* A = ws + WS_A;
    int img = blockIdx.x >> 3;
    int hgrp = blockIdx.x & 7;
    int t = threadIdx.x;
    int v = t >> 6;                 // wave = 16-row window
    int lane = t & 63;
    int R0 = hgrp * 64 + v * 16;
    const float* xb = x + (size_t)img * 262144 + (size_t)R0 * 512 + lane * 4;

    const float TH = 6.28318530717958647692f / 512.0f;
    float bc, bs;                   // e^{i theta R}, wave-uniform, R = burst base
    sincosf(TH * (float)R0, &bs, &bc);

    // acc[comp][q]: comp 0=s0, 1=ar1, 2=ai1, 3=ar2, 4=ai2, 5=ar3, 6=ai3
    float aA[7][4], aB[7][4];
#pragma unroll
    for (int c = 0; c < 7; ++c)
#pragma unroll
        for (int q = 0; q < 4; ++q) { aA[c][q] = 0.f; aB[c][q] = 0.f; }

    const float CJr[4] = {1.f, CJ1, CJ2, CJ3};
    const float SJr[4] = {0.f, SJ1, SJ2, SJ3};

#pragma unroll
    for (int b = 0; b < 4; ++b) {
        // 8 contiguous, independent 16B loads (rows R0+4b..+3, both halves)
        float4 L[8];
#pragma unroll
        for (int rr = 0; rr < 4; ++rr) {
            L[rr * 2 + 0] = *(const float4*)(xb + (size_t)(b * 4 + rr) * 512);
            L[rr * 2 + 1] = *(const float4*)(xb + (size_t)(b * 4 + rr) * 512 + 256);
        }
#pragma unroll
        for (int rr = 0; rr < 4; ++rr) {
            float c1 = bc * CJr[rr] - bs * SJr[rr];
            float s1 = bs * CJr[rr] + bc * SJr[rr];
            float c2 = c1 * c1 - s1 * s1;
            float s2 = 2.f * c1 * s1;
            float c3 = c1 * c2 - s1 * s2;
            float s3 = s1 * c2 + c1 * s2;
            float xa[4] = {L[rr * 2].x, L[rr * 2].y, L[rr * 2].z, L[rr * 2].w};
            float xbv[4] = {L[rr * 2 + 1].x, L[rr * 2 + 1].y, L[rr * 2 + 1].z, L[rr * 2 + 1].w};
#pragma unroll
            for (int q = 0; q < 4; ++q) {
                aA[0][q] += xa[q];
                aA[1][q] = fmaf(xa[q], c1, aA[1][q]);  aA[2][q] = fmaf(-xa[q], s1, aA[2][q]);
                aA[3][q] = fmaf(xa[q], c2, aA[3][q]);  aA[4][q] = fmaf(-xa[q], s2, aA[4][q]);
                aA[5][q] = fmaf(xa[q], c3, aA[5][q]);  aA[6][q] = fmaf(-xa[q], s3, aA[6][q]);
                aB[0][q] += xbv[q];
                aB[1][q] = fmaf(xbv[q], c1, aB[1][q]); aB[2][q] = fmaf(-xbv[q], s1, aB[2][q]);
                aB[3][q] = fmaf(xbv[q], c2, aB[3][q]); aB[4][q] = fmaf(-xbv[q], s2, aB[4][q]);
                aB[5][q] = fmaf(xbv[q], c3, aB[5][q]); aB[6][q] = fmaf(-xbv[q], s3, aB[6][q]);
            }
        }
        if (b < 3) {  // advance base phasor by 4 rows
            float nb = bc * CJ4 - bs * SJ4;
            bs = bs * CJ4 + bc * SJ4;
            bc = nb;
        }
    }

    // merge 4 waves via LDS; wave 0 stores
    if (v != 0) {
        float* r = &buf[v - 1][lane][0];
#pragma unroll
        for (int c = 0; c < 7; ++c)
#pragma unroll
            for (int q = 0; q < 4; ++q) {
                r[c * 4 + q] = aA[c][q];
                r[28 + c * 4 + q] = aB[c][q];
            }
    }
    __syncthreads();
    if (v == 0) {
#pragma unroll
        for (int u = 0; u < 3; ++u) {
            const float* r = &buf[u][lane][0];
#pragma unroll
            for (int c = 0; c < 7; ++c)
#pragma unroll
                for (int q = 0; q < 4; ++q) {
                    aA[c][q] += r[c * 4 + q];
                    aB[c][q] += r[28 + c * 4 + q];
                }
        }
        // planes: 0=s0, 1=zero, 2=ar1, 3=ai1, 4=ar2, 5=ai2, 6=ar3, 7=ai3
        float* Ab = A + (((size_t)img * NPART + hgrp) * 8) * 512 + lane * 4;
        const int pl[7] = {0, 2, 3, 4, 5, 6, 7};
#pragma unroll
        for (int c = 0; c < 7; ++c) {
            *(float4*)(Ab + (size_t)pl[c] * 512)       = make_float4(aA[c][0], aA[c][1], aA[c][2], aA[c][3]);
            *(float4*)(Ab + (size_t)pl[c] * 512 + 256) = make_float4(aB[c][0], aB[c][1], aB[c][2], aB[c][3]);
        }
        *(float4*)(Ab + 1 * 512)       = make_float4(0.f, 0.f, 0.f, 0.f);
        *(float4*)(Ab + 1 * 512 + 256) = make_float4(0.f, 0.f, 0.f, 0.f);
    }
}

// Blocks 0..767 = (img, seg): reduce 8 partials for 64 w, project 28 pairs.
// Block 768: build tabS.
__global__ __launch_bounds__(256) void k_proj(float* __restrict__ ws) {
    int t = threadIdx.x;
    const float TH = 6.28318530717958647692f / 512.0f;
    if (blockIdx.x == 768) {
        const int mv[6] = {0, 1, 2, -3, -2, -1};
        for (int h = t; h < 512; h += 256) {
            float* tsp = ws + WS_TS + h * 12;
#pragma unroll
            for (int i = 0; i < 6; ++i) {
                int r = ((mv[i] * h) % 512 + 512) & 511;
                float s, c;
                sincosf(TH * (float)r, &s, &c);
                tsp[2 * i] = c; tsp[2 * i + 1] = s;
            }
        }
        return;
    }
    __shared__ float As[8][64];
    const float* A = ws + WS_A;
    float* Pp = ws + WS_PP;
    int img = blockIdx.x >> 3;
    int seg = blockIdx.x & 7;

    {   // t -> (plane, w-pair); 8 upfront float2 loads over hg
        int plane = t >> 5;
        int wl = (t & 31) * 2;
        float2 L[8];
#pragma unroll
        for (int hg = 0; hg < NPART; ++hg)
            L[hg] = *(const float2*)(A + (((size_t)img * NPART + hg) * 8 + plane) * 512 + seg * 64 + wl);
        float ax = 0.f, ay = 0.f;
#pragma unroll
        for (int hg = 0; hg < NPART; ++hg) { ax += L[hg].x; ay += L[hg].y; }
        As[plane][wl] = ax;
        As[plane][wl + 1] = ay;
    }
    __syncthreads();

    if (t < 28) {
        int k = t / 7, mi = t % 7;
        float m = (float)(mi - 3);
        float cm, sm, pc, ps;
        sincosf(-m * TH, &sm, &cm);                       // step e^{-i m theta}
        sincosf(-m * TH * (float)(seg * 64), &ps, &pc);   // init e^{-i m theta w0}
        const float* Ar_ = &As[2 * k][0];
        const float* Ai_ = &As[2 * k + 1][0];
        float pre = 0.f, pim = 0.f;
#pragma unroll 4
        for (int j = 0; j < 64; ++j) {
            float Ar = Ar_[j], Ai = Ai_[j];
            pre += Ar * pc - Ai * ps;
            pim += Ar * ps + Ai * pc;
            float n = pc * cm - ps * sm;
            ps = ps * cm + pc * sm;
            pc = n;
        }
        float* o = Pp + ((size_t)img * 8 + seg) * 56;
        o[t * 2] = pre;
        o[t * 2 + 1] = pim;
    }
}

__global__ __launch_bounds__(256) void k_out(const float* __restrict__ ws,
                                             const float* __restrict__ w1,
                                             const float* __restrict__ b1,
                                             const float* __restrict__ w2,
                                             const float* __restrict__ b2,
                                             float* __restrict__ out) {
    const float* tabS = ws + WS_TS;
    const float* Pp = ws + WS_PP;
    __shared__ float F_lds[3][56];
    __shared__ float T[4][3][12];
    int t = threadIdx.x;
    int blk = blockIdx.x;
    int b = blk >> 7;
    int h0 = (blk & 127) << 2;

    if (t < 168) {
        int c = t / 56, comp = t % 56;
        const float* pp = Pp + ((size_t)(b * 3 + c) * 8) * 56 + comp;
        float s = 0.f;
#pragma unroll
        for (int g = 0; g < 8; ++g) s += pp[g * 56];
        F_lds[c][comp] = s;
    }

    float rw1[8][3], rb1[8], rw2[3][8], rb2[3];
#pragma unroll
    for (int f_ = 0; f_ < 8; ++f_) {
        rb1[f_] = b1[f_];
#pragma unroll
        for (int c = 0; c < 3; ++c) rw1[f_][c] = w1[f_ * 3 + c];
    }
#pragma unroll
    for (int c = 0; c < 3; ++c) {
        rb2[c] = b2[c];
#pragma unroll
        for (int f_ = 0; f_ < 8; ++f_) rw2[c][f_] = w2[c * 8 + f_];
    }
    __syncthreads();

    if (t < 72) {
        int rl = t / 18, rem = t % 18;
        int c = rem / 6, kc = rem % 6;
        int h = h0 + rl;
        const float* th = tabS + h * 12;
        int m_kc = (kc < 3) ? kc : kc - 6;
        const float inv = 1.0f / (512.0f * 512.0f);
        float tre = 0.f, tim = 0.f;
#pragma unroll
        for (int kr = 0; kr < 6; ++kr) {
            int kk, mi; float csign;
            if (kr < 3) { kk = kr;     mi = m_kc + 3; csign =  1.f; }
            else        { kk = 6 - kr; mi = 3 - m_kc; csign = -1.f; }
            int pair = kk * 7 + mi;
            float fr = F_lds[c][pair * 2] * inv;
            float fi = F_lds[c][pair * 2 + 1] * csign * inv;
            float cc = th[kr * 2], ss = th[kr * 2 + 1];
            tre += fr * cc - fi * ss;
            tim += fr * ss + fi * cc;
        }
        T[rl][c][kc * 2]     = tre;
        T[rl][c][kc * 2 + 1] = tim;
    }
    __syncthreads();

    int rl = t >> 6, lane = t & 63;
    int h = h0 + rl;
    float A0r[3], A0i[3], U1r[3], U1i[3], V1r[3], V1i[3];
    float U2r[3], U2i[3], V2r[3], V2i[3], Br[3], Bi[3];
#pragma unroll
    for (int c = 0; c < 3; ++c) {
        const float* Tc = T[rl][c];
        A0r[c] = Tc[0];  A0i[c] = Tc[1];
        float t1r = Tc[2],  t1i = Tc[3];
        float t2r = Tc[4],  t2i = Tc[5];
        float bmr = Tc[6],  bmi = Tc[7];
        float m2r = Tc[8],  m2i = Tc[9];
        float m1r = Tc[10], m1i = Tc[11];
        U1r[c] = t1r + m1r; U1i[c] = t1i + m1i;
        V1r[c] = t1r - m1r; V1i[c] = t1i - m1i;
        U2r[c] = t2r + m2r; U2i[c] = t2i + m2i;
        V2r[c] = t2r - m2r; V2i[c] = t2i - m2i;
        Br[c] = bmr; Bi[c] = bmi;
    }
    const float* tw = tabS + lane * 12;
    float c1 = tw[2], s1 = tw[3];
    float c2 = tw[4], s2 = tw[5];
    float c3 = tw[6], s3 = -tw[7];
    const float K = 0.70710678118654752440f;
    float* ob = out + ((size_t)(b * 3) * 512 + h) * 512;

#pragma unroll
    for (int j = 0; j < 8; ++j) {
        int w = lane + 64 * j;
        float lp[3];
#pragma unroll
        for (int c = 0; c < 3; ++c) {
            float re = A0r[c] + U1r[c] * c1 - V1i[c] * s1
                              + U2r[c] * c2 - V2i[c] * s2
                              + Br[c] * c3 + Bi[c] * s3;
            float im = A0i[c] + U1i[c] * c1 + V1r[c] * s1
                              + U2i[c] * c2 + V2r[c] * s2
                              + Bi[c] * c3 - Br[c] * s3;
            lp[c] = sqrtf(re * re + im * im);
        }
        float hid[8];
#pragma unroll
        for (int f_ = 0; f_ < 8; ++f_) {
            float v = rb1[f_] + lp[0] * rw1[f_][0] + lp[1] * rw1[f_][1] + lp[2] * rw1[f_][2];
            hid[f_] = fmaxf(v, 0.0f);
        }
#pragma unroll
        for (int c = 0; c < 3; ++c) {
            float y = rb2[c] + lp[c];
#pragma unroll
            for (int f_ = 0; f_ < 8; ++f_) y += hid[f_] * rw2[c][f_];
            y = fminf(fmaxf(y, 0.0f), 1.0f);
            ob[(size_t)c * 262144 + w] = y;
        }
        if (j < 7) {
            float nc1 = K * (c1 - s1), ns1 = K * (c1 + s1);
            float nc2 = -s2,           ns2 = c2;
            float nc3 = -K * (c3 + s3), ns3 = K * (c3 - s3);
            c1 = nc1; s1 = ns1; c2 = nc2; s2 = ns2; c3 = nc3; s3 = ns3;
        }
    }
}

extern "C" void kernel_launch(void* const* d_in, const int* in_sizes, int n_in,
                              void* d_out, int out_size, void* d_ws, size_t ws_size,
                              hipStream_t stream) {
    const float* x  = (const float*)d_in[0];
    const float* w1 = (const float*)d_in[1];
    const float* b1 = (const float*)d_in[2];
    const float* w2 = (const float*)d_in[3];
    const float* b2 = (const float*)d_in[4];
    float* out = (float*)d_out;
    float* ws = (float*)d_ws;

    hipLaunchKernelGGL(k_colsum, dim3(96 * 8), dim3(256), 0, stream, x, ws);
    hipLaunchKernelGGL(k_proj, dim3(769), dim3(256), 0, stream, ws);
    hipLaunchKernelGGL(k_out, dim3(4096), dim3(256), 0, stream, ws, w1, b1, w2, b2, out);
}